// Round 3
// baseline (955.741 us; speedup 1.0000x reference)
//
#include <hip/hip_runtime.h>
#include <math.h>

constexpr int B_ = 4;
constexpr int S_ = 2048;
constexpr int H_ = 16;
constexpr int HID_ = 2048;
constexpr int DK_ = 128;
constexpr int DV_ = 128;

constexpr int CH_ = 16;              // timesteps per chunk (WY chunk size)
constexpr int NC_ = 4;               // DV split across blocks
constexpr int COLS_ = DV_ / NC_;     // 32 columns per block
constexpr int NCHS_ = S_ / CH_;      // 128 chunks

constexpr int LKW4_ = 33;            // k/q row stride in float4 (32 data + 1 pad)
constexpr int LVW_ = 36;             // v/D/o row stride in floats (32 data + 4 pad)

// ---------------- DPP cross-lane helpers (VALU-latency, no DS pipe) --------
template <int CTRL>
__device__ __forceinline__ float dpp_add(float x) {
  int y = __builtin_amdgcn_update_dpp(0, __float_as_int(x), CTRL, 0xF, 0xF, true);
  return x + __int_as_float(y);
}
// butterfly sum over aligned 16-lane groups; every lane gets the total
__device__ __forceinline__ float sum16(float x) {
  x = dpp_add<0xB1>(x);   // quad_perm [1,0,3,2]  (xor 1)
  x = dpp_add<0x4E>(x);   // quad_perm [2,3,0,1]  (xor 2)
  x = dpp_add<0x141>(x);  // row_half_mirror      (xor 7)
  x = dpp_add<0x140>(x);  // row_mirror           (xor 15)
  return x;
}

// ---------------------------------------------------------------------------
// Gates: computes alpha (log-decay) and beta for all (b,s,h).
// ---------------------------------------------------------------------------
__global__ __launch_bounds__(256) void gates_kernel(
    const float* __restrict__ x, const float* __restrict__ Wa,
    const float* __restrict__ Wb, const float* __restrict__ dt_bias,
    const float* __restrict__ A_log, float* __restrict__ alpha,
    float* __restrict__ beta) {
  const int r0 = blockIdx.x * 4;
  const int w = threadIdx.x >> 6;
  const int lane = threadIdx.x & 63;

  const float4* x4 = reinterpret_cast<const float4*>(x);
  const float4* wbase = reinterpret_cast<const float4*>(w < 2 ? Wa : Wb);
  const int h0 = (w & 1) * 8;

  float acc[4][8];
#pragma unroll
  for (int i = 0; i < 4; ++i)
#pragma unroll
    for (int j = 0; j < 8; ++j) acc[i][j] = 0.f;

  for (int m = 0; m < 8; ++m) {
    const int kk = m * 64 + lane;
    float4 xv[4], wv[8];
#pragma unroll
    for (int i = 0; i < 4; ++i) xv[i] = x4[(size_t)(r0 + i) * (HID_ / 4) + kk];
#pragma unroll
    for (int j = 0; j < 8; ++j) wv[j] = wbase[(size_t)(h0 + j) * (HID_ / 4) + kk];
#pragma unroll
    for (int i = 0; i < 4; ++i)
#pragma unroll
      for (int j = 0; j < 8; ++j) {
        acc[i][j] = fmaf(xv[i].x, wv[j].x, acc[i][j]);
        acc[i][j] = fmaf(xv[i].y, wv[j].y, acc[i][j]);
        acc[i][j] = fmaf(xv[i].z, wv[j].z, acc[i][j]);
        acc[i][j] = fmaf(xv[i].w, wv[j].w, acc[i][j]);
      }
  }

  float myval = 0.f;
#pragma unroll
  for (int i = 0; i < 4; ++i)
#pragma unroll
    for (int j = 0; j < 8; ++j) {
      float v = sum16(acc[i][j]);
      v += __shfl_xor(v, 16, 64);
      v += __shfl_xor(v, 32, 64);
      if (lane == i * 8 + j) myval = v;
    }
  if (lane < 32) {
    const int i = lane >> 3, j = lane & 7;
    const int h = h0 + j;
    const int row = r0 + i;
    if (w < 2) {
      const float za = myval + dt_bias[h];
      const float sp = (za > 20.f) ? za : log1pf(expf(za));
      alpha[(size_t)row * H_ + h] = -expf(A_log[h]) * sp;  // log-decay
    } else {
      beta[(size_t)row * H_ + h] = myval;
    }
  }
}

// ---------------------------------------------------------------------------
// Chunked WY scan. Block = (dv-chunk c, head h, batch b), 512 threads.
// State slice 128x32 in registers: lane (sub=tid&15, col=tid>>4) owns rows
// sub*8..sub*8+7 of column col.
// LDS layout: k/q rows padded to 33 float4 (stride ≡ 4 banks -> P1 row reads
// 4-way instead of 16-way); slot swizzle ph=(d4&1)*16+(d4>>1) so fragment
// reads lk4[t*33 + {sub, 16+sub}] are consecutive slots (2-way, free) AND
// correspond to state rows 8*sub..8*sub+7. v/D/o rows padded to 36 floats
// (2-way, float4-aligned). Dots in P1 are permutation-invariant under ph.
// Per 16-step chunk:
//   P1: all-pairs dots (2 threads/pair, halves of DK), gate matrices
//       A (strict-lower, with beta_t), AttT (lower incl diag), gt, rr.
//   P3: KS/QS = k_t/q_t . S0_col via 8-FMA + sum16, lane sub keeps t==sub.
//   P4: 16-step triangular solve for D (only serial part).
//   P6: out = gt*QS + AttT.D (pure FMA); state = gt15*S0 + sum rr_i k_i D_i.
//   P7: coalesced float4 out store (full lines -> no RMW write amp).
// ---------------------------------------------------------------------------
__global__ __launch_bounds__(512) void scan_kernel(
    const float* __restrict__ qg, const float* __restrict__ kg,
    const float* __restrict__ vg, const float* __restrict__ alphag,
    const float* __restrict__ betag, float* __restrict__ outg) {
  const int c = blockIdx.x;
  const int h = blockIdx.y;
  const int b = blockIdx.z;
  const int tid = threadIdx.x;
  const int sub = tid & 15;
  const int col = tid >> 4;  // 0..31

  __shared__ __align__(16) float lk[CH_ * LKW4_ * 4];
  __shared__ __align__(16) float lq[CH_ * LKW4_ * 4];
  __shared__ __align__(16) float lv[CH_ * LVW_];
  __shared__ float lab[CH_], lbt[CH_], lgt[CH_], lrr[CH_];
  __shared__ float lA[CH_ * CH_];     // A[t][i], zero for i>=t
  __shared__ float lAttT[CH_ * CH_];  // AttT[i][t] = att[t][i], zero for i>t
  __shared__ __align__(16) float lD[CH_ * LVW_];
  __shared__ __align__(16) float lo[CH_ * LVW_];

  const float4* k4 = reinterpret_cast<const float4*>(kg);
  const float4* q4 = reinterpret_cast<const float4*>(qg);
  const float4* v4 = reinterpret_cast<const float4*>(vg);
  float4* lk4 = reinterpret_cast<float4*>(lk);
  float4* lq4 = reinterpret_cast<float4*>(lq);
  float4* lv4 = reinterpret_cast<float4*>(lv);
  const float4* lo4 = reinterpret_cast<const float4*>(lo);

  // staging coords: thread stages k/q float4 at (u0, d4); swizzled slot ph
  const int u0 = tid >> 5, d4 = tid & 31;
  const int ph = (d4 & 1) * 16 + (d4 >> 1);

  float4 pk = {}, pq = {}, pv = {};
  float pg = 0.f, pb = 0.f;

  auto loadRegs = [&](int s0) {
    const size_t base = ((size_t)(b * S_ + s0 + u0) * H_ + h) * (DK_ / 4) + d4;
    pk = k4[base];
    pq = q4[base];
    if (tid < 128) {
      const int uu = tid >> 3, e = tid & 7;
      pv = v4[((size_t)(b * S_ + s0 + uu) * H_ + h) * (DV_ / 4) + c * (COLS_ / 4) + e];
    }
    if (tid >= 128 && tid < 128 + CH_)
      pg = alphag[(size_t)(b * S_ + s0 + (tid - 128)) * H_ + h];
    if (tid >= 160 && tid < 160 + CH_)
      pb = betag[(size_t)(b * S_ + s0 + (tid - 160)) * H_ + h];
  };

  auto writeLDS = [&]() {
    lk4[u0 * LKW4_ + ph] = pk;
    lq4[u0 * LKW4_ + ph] = pq;
    if (tid < 128) {
      const int uu = tid >> 3, e = tid & 7;
      lv4[uu * (LVW_ / 4) + e] = pv;
    }
    if (tid >= 128 && tid < 128 + CH_) lab[tid - 128] = pg;
    if (tid >= 160 && tid < 160 + CH_) lbt[tid - 160] = pb;
  };

  float st[8];  // rows sub*8+r of column col
#pragma unroll
  for (int r = 0; r < 8; ++r) st[r] = 0.f;

  loadRegs(0);
  writeLDS();
  __syncthreads();

  for (int ci = 0; ci < NCHS_; ++ci) {
    const int s0 = ci * CH_;
    if (ci + 1 < NCHS_) loadRegs(s0 + CH_);  // global prefetch for next chunk

    // ---------- P1: pair dots + gate matrices -----------------------------
    {
      const int p = tid >> 1, half = tid & 1;
      const int t = p >> 4, i = p & 15;
      const float4* kt = &lk4[t * LKW4_ + half * 16];
      const float4* ki = &lk4[i * LKW4_ + half * 16];
      const float4* qt = &lq4[t * LKW4_ + half * 16];
      float dp = 0.f, dq = 0.f;
#pragma unroll
      for (int e = 0; e < 16; ++e) {
        const float4 a = kt[e], bb = ki[e], qq = qt[e];
        dp = fmaf(a.x, bb.x, fmaf(a.y, bb.y, fmaf(a.z, bb.z, fmaf(a.w, bb.w, dp))));
        dq = fmaf(qq.x, bb.x, fmaf(qq.y, bb.y, fmaf(qq.z, bb.z, fmaf(qq.w, bb.w, dq))));
      }
      dp += __shfl_xor(dp, 1, 64);
      dq += __shfl_xor(dq, 1, 64);
      // la_t - la_i (= 0 when i >= t), predicated sum of staged alphas
      float ld = 0.f;
#pragma unroll
      for (int j = 1; j < 16; ++j) {
        const float aj = lab[j];
        ld += (j > i && j <= t) ? aj : 0.f;
      }
      if (half == 0) {
        const float r = expf(ld);
        lA[t * 16 + i] = (i < t) ? r * lbt[t] * dp : 0.f;
        lAttT[i * 16 + t] = (i <= t) ? r * dq : 0.f;
        if (i == 0) lgt[t] = expf(ld + lab[0]);  // exp(la_t), inclusive
        if (t == 15) lrr[i] = r;                 // exp(la_15 - la_i)
      }
    }

    // ---------- P3: KS/QS against incoming state --------------------------
    float ks_mine = 0.f, qs_mine = 0.f;
#pragma unroll
    for (int t = 0; t < CH_; ++t) {
      const float4 ka = lk4[t * LKW4_ + sub], kb = lk4[t * LKW4_ + 16 + sub];
      const float4 qa = lq4[t * LKW4_ + sub], qb = lq4[t * LKW4_ + 16 + sub];
      float ks = 0.f, qs = 0.f;
      ks = fmaf(ka.x, st[0], ks); ks = fmaf(ka.y, st[1], ks);
      ks = fmaf(ka.z, st[2], ks); ks = fmaf(ka.w, st[3], ks);
      ks = fmaf(kb.x, st[4], ks); ks = fmaf(kb.y, st[5], ks);
      ks = fmaf(kb.z, st[6], ks); ks = fmaf(kb.w, st[7], ks);
      qs = fmaf(qa.x, st[0], qs); qs = fmaf(qa.y, st[1], qs);
      qs = fmaf(qa.z, st[2], qs); qs = fmaf(qa.w, st[3], qs);
      qs = fmaf(qb.x, st[4], qs); qs = fmaf(qb.y, st[5], qs);
      qs = fmaf(qb.z, st[6], qs); qs = fmaf(qb.w, st[7], qs);
      ks = sum16(ks);
      qs = sum16(qs);
      if (sub == t) { ks_mine = ks; qs_mine = qs; }
    }

    __syncthreads();  // bar A: lA/lAttT/lgt/lrr visible

    // ---------- P4: triangular solve for D --------------------------------
    {
      float areg[CH_];
#pragma unroll
      for (int t = 0; t < CH_; ++t) areg[t] = lA[t * 16 + sub];
      const float bmine = lbt[sub] * (lv[sub * LVW_ + col] - lgt[sub] * ks_mine);
      float d = 0.f;
#pragma unroll
      for (int t = 0; t < CH_; ++t) {
        const float s = sum16(areg[t] * d);
        if (sub == t) d = bmine - s;
      }
      lD[sub * LVW_ + col] = d;
    }

    __syncthreads();  // bar B: lD visible

    // ---------- P6: outputs + state update --------------------------------
    {
      float dd[CH_], at[CH_];
#pragma unroll
      for (int i = 0; i < CH_; ++i) dd[i] = lD[i * LVW_ + col];
#pragma unroll
      for (int i = 0; i < CH_; ++i) at[i] = lAttT[i * 16 + sub];
      float o = lgt[sub] * qs_mine;
#pragma unroll
      for (int i = 0; i < CH_; ++i) o = fmaf(at[i], dd[i], o);
      lo[sub * LVW_ + col] = o;

      const float g15 = lgt[15];
#pragma unroll
      for (int r = 0; r < 8; ++r) st[r] *= g15;
#pragma unroll
      for (int i = 0; i < CH_; ++i) {
        const float e = lrr[i] * dd[i];
        const float4 ka = lk4[i * LKW4_ + sub], kb = lk4[i * LKW4_ + 16 + sub];
        st[0] = fmaf(ka.x, e, st[0]); st[1] = fmaf(ka.y, e, st[1]);
        st[2] = fmaf(ka.z, e, st[2]); st[3] = fmaf(ka.w, e, st[3]);
        st[4] = fmaf(kb.x, e, st[4]); st[5] = fmaf(kb.y, e, st[5]);
        st[6] = fmaf(kb.z, e, st[6]); st[7] = fmaf(kb.w, e, st[7]);
      }
    }

    __syncthreads();  // bar C: lo visible; all lk/lq/lv reads done

    // ---------- P7: coalesced out store + stage next chunk ----------------
    if (tid < 128) {
      const int t = tid >> 3, e = tid & 7;
      *reinterpret_cast<float4*>(
          &outg[((size_t)(b * S_ + s0 + t) * H_ + h) * DV_ + c * COLS_ + e * 4]) =
          lo4[t * (LVW_ / 4) + e];
    }
    if (ci + 1 < NCHS_) writeLDS();

    __syncthreads();  // bar D: next chunk's lk/lq/lv/lab/lbt visible
  }
}

extern "C" void kernel_launch(void* const* d_in, const int* in_sizes, int n_in,
                              void* d_out, int out_size, void* d_ws, size_t ws_size,
                              hipStream_t stream) {
  const float* x = (const float*)d_in[0];
  const float* q = (const float*)d_in[1];
  const float* k = (const float*)d_in[2];
  const float* v = (const float*)d_in[3];
  const float* Wa = (const float*)d_in[4];
  const float* Wb = (const float*)d_in[5];
  const float* dtb = (const float*)d_in[6];
  const float* Alog = (const float*)d_in[7];
  float* out = (float*)d_out;

  float* alpha = (float*)d_ws;
  float* beta = alpha + (size_t)B_ * S_ * H_;

  gates_kernel<<<B_ * S_ / 4, 256, 0, stream>>>(x, Wa, Wb, dtb, Alog, alpha, beta);
  scan_kernel<<<dim3(NC_, H_, B_), 512, 0, stream>>>(q, k, v, alpha, beta, out);
}

// Round 5
// 608.689 us; speedup vs baseline: 1.5702x; 1.5702x over previous
//
#include <hip/hip_runtime.h>
#include <math.h>

constexpr int B_ = 4;
constexpr int S_ = 2048;
constexpr int H_ = 16;
constexpr int HID_ = 2048;
constexpr int DK_ = 128;
constexpr int DV_ = 128;

constexpr int CH_ = 16;              // timesteps per LDS chunk
constexpr int NC_ = 4;               // DV split across blocks
constexpr int COLS_ = DV_ / NC_;     // 32 columns per block
constexpr int NCHS_ = S_ / CH_;      // 128 chunks

typedef float f32x4_ __attribute__((ext_vector_type(4)));  // native vec for nt-store

// ---------------- DPP cross-lane helpers (VALU-latency, no DS pipe) --------
template <int CTRL>
__device__ __forceinline__ float dpp_add(float x) {
  int y = __builtin_amdgcn_update_dpp(0, __float_as_int(x), CTRL, 0xF, 0xF, true);
  return x + __int_as_float(y);
}
// butterfly sum over aligned 16-lane groups; every lane gets the total
__device__ __forceinline__ float sum16(float x) {
  x = dpp_add<0xB1>(x);   // quad_perm [1,0,3,2]  (xor 1)
  x = dpp_add<0x4E>(x);   // quad_perm [2,3,0,1]  (xor 2)
  x = dpp_add<0x141>(x);  // row_half_mirror      (xor 7)
  x = dpp_add<0x140>(x);  // row_mirror           (xor 15)
  return x;
}
__device__ __forceinline__ float swz_xor16(float x) {
  // BitMode swizzle: lane ^= 16 within each 32-lane group
  int y = __builtin_amdgcn_ds_swizzle(__float_as_int(x), 0x401F);
  return __int_as_float(y);
}

// ---------------------------------------------------------------------------
// Gates: decay/beta for all (b,s,h). Verified in round 1.
// ---------------------------------------------------------------------------
__global__ __launch_bounds__(256) void gates_kernel(
    const float* __restrict__ x, const float* __restrict__ Wa,
    const float* __restrict__ Wb, const float* __restrict__ dt_bias,
    const float* __restrict__ A_log, float* __restrict__ decay,
    float* __restrict__ beta) {
  const int r0 = blockIdx.x * 4;
  const int w = threadIdx.x >> 6;
  const int lane = threadIdx.x & 63;

  const float4* x4 = reinterpret_cast<const float4*>(x);
  const float4* wbase = reinterpret_cast<const float4*>(w < 2 ? Wa : Wb);
  const int h0 = (w & 1) * 8;

  float acc[4][8];
#pragma unroll
  for (int i = 0; i < 4; ++i)
#pragma unroll
    for (int j = 0; j < 8; ++j) acc[i][j] = 0.f;

  for (int m = 0; m < 8; ++m) {
    const int kk = m * 64 + lane;
    float4 xv[4], wv[8];
#pragma unroll
    for (int i = 0; i < 4; ++i) xv[i] = x4[(size_t)(r0 + i) * (HID_ / 4) + kk];
#pragma unroll
    for (int j = 0; j < 8; ++j) wv[j] = wbase[(size_t)(h0 + j) * (HID_ / 4) + kk];
#pragma unroll
    for (int i = 0; i < 4; ++i)
#pragma unroll
      for (int j = 0; j < 8; ++j) {
        acc[i][j] = fmaf(xv[i].x, wv[j].x, acc[i][j]);
        acc[i][j] = fmaf(xv[i].y, wv[j].y, acc[i][j]);
        acc[i][j] = fmaf(xv[i].z, wv[j].z, acc[i][j]);
        acc[i][j] = fmaf(xv[i].w, wv[j].w, acc[i][j]);
      }
  }

  float myval = 0.f;
#pragma unroll
  for (int i = 0; i < 4; ++i)
#pragma unroll
    for (int j = 0; j < 8; ++j) {
      float v = sum16(acc[i][j]);
      v += __shfl_xor(v, 16, 64);
      v += __shfl_xor(v, 32, 64);
      if (lane == i * 8 + j) myval = v;
    }
  if (lane < 32) {
    const int i = lane >> 3, j = lane & 7;
    const int h = h0 + j;
    const int row = r0 + i;
    if (w < 2) {
      const float za = myval + dt_bias[h];
      const float sp = (za > 20.f) ? za : log1pf(expf(za));
      decay[(size_t)row * H_ + h] = expf(-expf(A_log[h]) * sp);
    } else {
      beta[(size_t)row * H_ + h] = myval;
    }
  }
}

// ---------------------------------------------------------------------------
// Serial scan (round-1 verified math), de-flabbed:
//  - 16-step chunk loop fully unrolled; frags in explicit double-buffered
//    registers (literal indices after unroll -> no struct copies, no scratch);
//  - all LDS frag reads are base + immediate offset (zero per-step addr math);
//  - outputs staged in lo[] and stored as full-line float4 (no RMW write amp);
//  - XCD-swizzled blockIdx: the 4 DV-blocks of one (b,h) share an XCD L2.
// Block = 512 thr: sub=tid&15 owns rows 8sub..8sub+7 of col=tid>>4.
// k/q LDS: per step 32 float4 slots, slot ph=(d4&1)*16+(d4>>1) so fragment
// reads lk4[u*32 + {sub, 16+sub}] give rows 8sub..+3 / 8sub+4..+7.
// out_t = g*(q.s_prev) + (q.k)*delta, qk precomputed at staging.
// ---------------------------------------------------------------------------
__global__ __launch_bounds__(512) void scan_kernel(
    const float* __restrict__ qg, const float* __restrict__ kg,
    const float* __restrict__ vg, const float* __restrict__ decay,
    const float* __restrict__ betag, float* __restrict__ outg) {
  // XCD swizzle: id = (g&7) + 8*c + 32*(g>>3), g = bh-group. id%8 == g&7.
  const int id = blockIdx.x;
  const int g_ = (id & 7) | ((id >> 5) << 3);
  const int c = (id >> 3) & 3;
  const int h = g_ & 15;
  const int b = g_ >> 4;
  const int tid = threadIdx.x;
  const int sub = tid & 15;
  const int col = tid >> 4;  // 0..31

  __shared__ __align__(16) float lk[CH_ * DK_];
  __shared__ __align__(16) float lq[CH_ * DK_];
  __shared__ __align__(16) float lv[CH_ * COLS_];
  __shared__ __align__(16) float lgbq[CH_ * 4];   // (g, beta, qk, pad)
  __shared__ __align__(16) float lo[CH_ * COLS_];

  const float4* k4 = reinterpret_cast<const float4*>(kg);
  const float4* q4 = reinterpret_cast<const float4*>(qg);
  const float4* v4 = reinterpret_cast<const float4*>(vg);
  float4* lk4 = reinterpret_cast<float4*>(lk);
  float4* lq4 = reinterpret_cast<float4*>(lq);
  float4* lv4 = reinterpret_cast<float4*>(lv);
  const f32x4_* lo4n = reinterpret_cast<const f32x4_*>(lo);

  // staging: thread stages one k/q float4 at (u0, d4), swizzled slot ph
  const int u0 = tid >> 5, d4 = tid & 31;
  const int ph = (d4 & 1) * 16 + (d4 >> 1);

  float4 pk = {}, pq = {}, pv = {};
  float pg = 0.f, pb = 0.f;

  auto loadRegs = [&](int s0) {
    const size_t base = ((size_t)(b * S_ + s0 + u0) * H_ + h) * (DK_ / 4) + d4;
    pk = k4[base];
    pq = q4[base];
    if (tid < 128) {
      const int uu = tid >> 3, e = tid & 7;
      pv = v4[((size_t)(b * S_ + s0 + uu) * H_ + h) * (DV_ / 4) + c * (COLS_ / 4) + e];
    }
    if (tid >= 128 && tid < 128 + CH_)
      pg = decay[(size_t)(b * S_ + s0 + (tid - 128)) * H_ + h];
    if (tid >= 160 && tid < 160 + CH_)
      pb = betag[(size_t)(b * S_ + s0 + (tid - 160)) * H_ + h];
  };

  auto writeLDS = [&]() {
    lk4[u0 * 32 + ph] = pk;
    lq4[u0 * 32 + ph] = pq;
    if (tid < 128) {
      const int uu = tid >> 3, e = tid & 7;
      lv4[uu * (COLS_ / 4) + e] = pv;
    }
    if (tid >= 128 && tid < 128 + CH_) lgbq[(tid - 128) * 4 + 0] = pg;
    if (tid >= 160 && tid < 160 + CH_) lgbq[(tid - 160) * 4 + 1] = pb;
    // qk[u] = q_u . k_u : per-lane dot4 partials reduced over the 32 lanes of u
    float p = fmaf(pq.x, pk.x, fmaf(pq.y, pk.y, fmaf(pq.z, pk.z, pq.w * pk.w)));
    p = sum16(p);
    p += swz_xor16(p);
    if ((tid & 31) == 0) lgbq[u0 * 4 + 2] = p;
  };

  float st[8];  // rows sub*8+r of column col
#pragma unroll
  for (int r = 0; r < 8; ++r) st[r] = 0.f;

  // double-buffered fragment registers (indices literal after unroll)
  float4 kA[2], kB[2], qA[2], qB[2], gq[2];
  float fv[2];

  loadRegs(0);
  writeLDS();
  __syncthreads();

  for (int ci = 0; ci < NCHS_; ++ci) {
    const int s0 = ci * CH_;
    if (ci + 1 < NCHS_) loadRegs(s0 + CH_);  // global prefetch for next chunk

    // prime buffer 0
    kA[0] = lk4[0 * 32 + sub];
    kB[0] = lk4[0 * 32 + 16 + sub];
    qA[0] = lq4[0 * 32 + sub];
    qB[0] = lq4[0 * 32 + 16 + sub];
    fv[0] = lv[0 * COLS_ + col];
    gq[0] = *reinterpret_cast<const float4*>(&lgbq[0]);

#pragma unroll
    for (int u = 0; u < CH_; ++u) {
      const int p = u & 1;
      if (u + 1 < CH_) {
        const int n = p ^ 1;
        kA[n] = lk4[(u + 1) * 32 + sub];
        kB[n] = lk4[(u + 1) * 32 + 16 + sub];
        qA[n] = lq4[(u + 1) * 32 + sub];
        qB[n] = lq4[(u + 1) * 32 + 16 + sub];
        fv[n] = lv[(u + 1) * COLS_ + col];
        gq[n] = *reinterpret_cast<const float4*>(&lgbq[(u + 1) * 4]);
      }
      const float gg = gq[p].x, bt = gq[p].y, qk = gq[p].z;
      float vp = kA[p].x * st[0];
      float op = qA[p].x * st[0];
      vp = fmaf(kA[p].y, st[1], vp); op = fmaf(qA[p].y, st[1], op);
      vp = fmaf(kA[p].z, st[2], vp); op = fmaf(qA[p].z, st[2], op);
      vp = fmaf(kA[p].w, st[3], vp); op = fmaf(qA[p].w, st[3], op);
      vp = fmaf(kB[p].x, st[4], vp); op = fmaf(qB[p].x, st[4], op);
      vp = fmaf(kB[p].y, st[5], vp); op = fmaf(qB[p].y, st[5], op);
      vp = fmaf(kB[p].z, st[6], vp); op = fmaf(qB[p].z, st[6], op);
      vp = fmaf(kB[p].w, st[7], vp); op = fmaf(qB[p].w, st[7], op);
      vp = sum16(vp);
      op = sum16(op);
      const float dlt = (fv[p] - gg * vp) * bt;
      st[0] = fmaf(kA[p].x, dlt, st[0] * gg);
      st[1] = fmaf(kA[p].y, dlt, st[1] * gg);
      st[2] = fmaf(kA[p].z, dlt, st[2] * gg);
      st[3] = fmaf(kA[p].w, dlt, st[3] * gg);
      st[4] = fmaf(kB[p].x, dlt, st[4] * gg);
      st[5] = fmaf(kB[p].y, dlt, st[5] * gg);
      st[6] = fmaf(kB[p].z, dlt, st[6] * gg);
      st[7] = fmaf(kB[p].w, dlt, st[7] * gg);
      if (sub == 0) lo[u * COLS_ + col] = fmaf(qk, dlt, gg * op);
    }

    __syncthreads();  // steps done: lo complete, lk/lq/lv/lgbq reads done

    // coalesced full-line out store (nontemporal, native vec type)
    if (tid < 128) {
      const int t = tid >> 3, e = tid & 7;
      __builtin_nontemporal_store(
          lo4n[t * (COLS_ / 4) + e],
          reinterpret_cast<f32x4_*>(
              &outg[((size_t)(b * S_ + s0 + t) * H_ + h) * DV_ + c * COLS_ + e * 4]));
    }
    if (ci + 1 < NCHS_) writeLDS();

    __syncthreads();  // next chunk's LDS visible
  }
}

extern "C" void kernel_launch(void* const* d_in, const int* in_sizes, int n_in,
                              void* d_out, int out_size, void* d_ws, size_t ws_size,
                              hipStream_t stream) {
  const float* x = (const float*)d_in[0];
  const float* q = (const float*)d_in[1];
  const float* k = (const float*)d_in[2];
  const float* v = (const float*)d_in[3];
  const float* Wa = (const float*)d_in[4];
  const float* Wb = (const float*)d_in[5];
  const float* dtb = (const float*)d_in[6];
  const float* Alog = (const float*)d_in[7];
  float* out = (float*)d_out;

  float* decay = (float*)d_ws;
  float* beta = decay + (size_t)B_ * S_ * H_;

  gates_kernel<<<B_ * S_ / 4, 256, 0, stream>>>(x, Wa, Wb, dtb, Alog, decay, beta);
  scan_kernel<<<256, 512, 0, stream>>>(q, k, v, decay, beta, out);
}